// Round 5
// baseline (488.371 us; speedup 1.0000x reference)
//
#include <hip/hip_runtime.h>
#include <hip/hip_bf16.h>

#define NROWS 8192
#define DIM 512
#define LST2 40  // BK=32 LDS row stride in shorts (32 data + 8 pad; rows 16B-aligned)

typedef __attribute__((ext_vector_type(8))) short bf16x8;
typedef __attribute__((ext_vector_type(4))) float f32x4;
typedef __attribute__((ext_vector_type(4))) unsigned short u16x4;

__device__ __forceinline__ float bf2f(unsigned short u) {
    return __uint_as_float(((unsigned int)u) << 16);
}
__device__ __forceinline__ unsigned short f2bf(float f) {
    unsigned int b = __float_as_uint(f);
    return (unsigned short)((b + 0x7FFFu + ((b >> 16) & 1u)) >> 16);
}
// monotone float->uint key: a<b (float) <=> key(a)<key(b) (uint)
__device__ __forceinline__ unsigned int fkey(float f) {
    unsigned int b = __float_as_uint(f);
    return (b & 0x80000000u) ? ~b : (b | 0x80000000u);
}

// ---------------------------------------------------------------- k_split
// fp32 xs -> bf16 hi plane + bf16 lo plane (lo = round(x - float(hi)))
__global__ __launch_bounds__(256) void k_split(const float* __restrict__ xs,
                                               unsigned short* __restrict__ hi,
                                               unsigned short* __restrict__ lo) {
    const int i4 = blockIdx.x * 256 + threadIdx.x;  // float4 index
    const float4 f = ((const float4*)xs)[i4];
    float v[4] = {f.x, f.y, f.z, f.w};
    u16x4 h, l;
#pragma unroll
    for (int i = 0; i < 4; ++i) {
        const unsigned short hs = f2bf(v[i]);
        h[i] = hs;
        l[i] = f2bf(v[i] - bf2f(hs));
    }
    *(u16x4*)(hi + (size_t)i4 * 4) = h;
    *(u16x4*)(lo + (size_t)i4 * 4) = l;
}

// ---------------------------------------------------------------- k_sq_init
// sq[row] = sum_k xs[row,k]^2 (fp32); init nn[row] = ~0ull for atomicMin
__global__ __launch_bounds__(256) void k_sq_init(const float* __restrict__ xs,
                                                 float* __restrict__ sq,
                                                 unsigned long long* __restrict__ nn) {
    const int wave = threadIdx.x >> 6, lane = threadIdx.x & 63;
    const int row = blockIdx.x * 4 + wave;
    const float4* xr = (const float4*)(xs + (size_t)row * DIM);
    const float4 a = xr[lane], b = xr[lane + 64];
    float s = 0.f;
    s = fmaf(a.x, a.x, s); s = fmaf(a.y, a.y, s);
    s = fmaf(a.z, a.z, s); s = fmaf(a.w, a.w, s);
    s = fmaf(b.x, b.x, s); s = fmaf(b.y, b.y, s);
    s = fmaf(b.z, b.z, s); s = fmaf(b.w, b.w, s);
#pragma unroll
    for (int d = 32; d; d >>= 1) s += __shfl_xor(s, d);
    if (lane == 0) { sq[row] = s; nn[row] = ~0ull; }
}

// ---------------------------------------------------------------- k_nn
// Fused distance + argmin, split-bf16 (hi/lo) 3-MFMA per tile-step.
// Tile 128(i) x 128(j), K=512 in BK=32 steps. grid = (64 i-tiles, 8 j-chunks)
// d2 error ~1e-4 vs NN d^2 gaps O(100): argmin exact.
__global__ __launch_bounds__(256) void k_nn(const unsigned short* __restrict__ xh,
                                            const unsigned short* __restrict__ xl,
                                            const float* __restrict__ sq,
                                            unsigned long long* __restrict__ nn) {
    __shared__ __align__(16) unsigned short lAh[128 * LST2];
    __shared__ __align__(16) unsigned short lAl[128 * LST2];
    __shared__ __align__(16) unsigned short lBh[128 * LST2];
    __shared__ __align__(16) unsigned short lBl[128 * LST2];
    const int tid = threadIdx.x;
    const int wave = tid >> 6, lane = tid & 63, quad = lane >> 4, ln = lane & 15;
    const int i0 = blockIdx.x * 128;
    const int jbase = blockIdx.y * 1024;
    const int m_off = (wave & 1) * 64, n_off = (wave >> 1) * 64;

    float minv[16];
    int mini[16];
#pragma unroll
    for (int t = 0; t < 16; ++t) { minv[t] = __builtin_inff(); mini[t] = 0; }

    for (int jt = 0; jt < 8; ++jt) {
        const int j0 = jbase + jt * 128;
        f32x4 acc[4][4];
#pragma unroll
        for (int a = 0; a < 4; ++a)
#pragma unroll
            for (int b = 0; b < 4; ++b) acc[a][b] = (f32x4){0.f, 0.f, 0.f, 0.f};

        for (int kt = 0; kt < 16; ++kt) {
            __syncthreads();
#pragma unroll
            for (int r = 0; r < 2; ++r) {
                const int idx = r * 256 + tid;
                const int row = idx >> 2, c = idx & 3;
                const size_t ga = (size_t)(i0 + row) * DIM + kt * 32 + c * 8;
                const size_t gb = (size_t)(j0 + row) * DIM + kt * 32 + c * 8;
                *(uint4*)(lAh + row * LST2 + c * 8) = *(const uint4*)(xh + ga);
                *(uint4*)(lAl + row * LST2 + c * 8) = *(const uint4*)(xl + ga);
                *(uint4*)(lBh + row * LST2 + c * 8) = *(const uint4*)(xh + gb);
                *(uint4*)(lBl + row * LST2 + c * 8) = *(const uint4*)(xl + gb);
            }
            __syncthreads();
            bf16x8 ah[4], al[4], bh[4], bl[4];
#pragma unroll
            for (int ms = 0; ms < 4; ++ms) {
                const int row = m_off + ms * 16 + ln;
                ah[ms] = *(const bf16x8*)(lAh + row * LST2 + quad * 8);
                al[ms] = *(const bf16x8*)(lAl + row * LST2 + quad * 8);
            }
#pragma unroll
            for (int ns = 0; ns < 4; ++ns) {
                const int row = n_off + ns * 16 + ln;
                bh[ns] = *(const bf16x8*)(lBh + row * LST2 + quad * 8);
                bl[ns] = *(const bf16x8*)(lBl + row * LST2 + quad * 8);
            }
#pragma unroll
            for (int ms = 0; ms < 4; ++ms)
#pragma unroll
                for (int ns = 0; ns < 4; ++ns) {
                    acc[ms][ns] = __builtin_amdgcn_mfma_f32_16x16x32_bf16(
                        ah[ms], bh[ns], acc[ms][ns], 0, 0, 0);
                    acc[ms][ns] = __builtin_amdgcn_mfma_f32_16x16x32_bf16(
                        ah[ms], bl[ns], acc[ms][ns], 0, 0, 0);
                    acc[ms][ns] = __builtin_amdgcn_mfma_f32_16x16x32_bf16(
                        al[ms], bh[ns], acc[ms][ns], 0, 0, 0);
                }
        }
        float sqj[4];
#pragma unroll
        for (int ns = 0; ns < 4; ++ns) sqj[ns] = sq[j0 + n_off + ns * 16 + ln];
        const bool diag = (j0 == i0);
#pragma unroll
        for (int ms = 0; ms < 4; ++ms)
#pragma unroll
            for (int v = 0; v < 4; ++v) {
                const int gi = i0 + m_off + ms * 16 + quad * 4 + v;
                const int t = ms * 4 + v;
#pragma unroll
                for (int ns = 0; ns < 4; ++ns) {
                    const int gj = j0 + n_off + ns * 16 + ln;
                    float d2 = fmaf(-2.f, acc[ms][ns][v], sqj[ns]);
                    if (diag && gj == gi) d2 = __builtin_inff();
                    if (d2 < minv[t]) { minv[t] = d2; mini[t] = gj; }
                }
            }
    }
#pragma unroll
    for (int t = 0; t < 16; ++t) {
        unsigned long long p =
            (((unsigned long long)fkey(minv[t])) << 32) | (unsigned int)mini[t];
#pragma unroll
        for (int d = 1; d < 16; d <<= 1) {
            unsigned long long o = __shfl_xor(p, d);
            p = (o < p) ? o : p;
        }
        if (ln == 0) {
            const int ms = t >> 2, v = t & 3;
            const int gi = i0 + m_off + ms * 16 + quad * 4 + v;
            atomicMin(&nn[gi], p);
        }
    }
}

// ---------------------------------------------------------------- k_l1f
// EXACT fp32: P = x@W1^T, Q = x0@W1^T -> A1 = Q+b1, U1 = P-Q.
// Wave = one row, lane = output n. W1 staged transposed in LDS k-tiles.
__global__ __launch_bounds__(256) void k_l1f(const float* __restrict__ xs,
                                             const unsigned long long* __restrict__ nn,
                                             const float* __restrict__ W1,
                                             const float* __restrict__ b1,
                                             float* __restrict__ A1,
                                             float* __restrict__ U1) {
    __shared__ float W1T[128][64];  // 32 KB, one k-tile transposed
    const int tid = threadIdx.x, wave = tid >> 6, lane = tid & 63;
    const int row = blockIdx.x * 4 + wave;
    const unsigned int idx = (unsigned int)(nn[row] & 0xFFFFFFFFull) & 8191u;

    float accP = 0.f, accQ = 0.f;
    for (int kt = 0; kt < 4; ++kt) {
        __syncthreads();
        {   // stage W1T[kk][n] <- W1[n][kt*128+kk]
            const int n = tid >> 2;
            const int kb = (tid & 3) * 32;
            const float* src = W1 + (size_t)n * DIM + kt * 128 + kb;
#pragma unroll
            for (int i = 0; i < 32; i += 4) {
                const float4 v = *(const float4*)(src + i);
                W1T[kb + i + 0][n] = v.x;
                W1T[kb + i + 1][n] = v.y;
                W1T[kb + i + 2][n] = v.z;
                W1T[kb + i + 3][n] = v.w;
            }
        }
        __syncthreads();
        const float xv0 = xs[(size_t)row * DIM + kt * 128 + lane];
        const float xv1 = xs[(size_t)row * DIM + kt * 128 + 64 + lane];
        const float x0v0 = xs[(size_t)idx * DIM + kt * 128 + lane];
        const float x0v1 = xs[(size_t)idx * DIM + kt * 128 + 64 + lane];
#pragma unroll
        for (int k = 0; k < 64; ++k) {
            const float w = W1T[k][lane];
            accP = fmaf(__shfl(xv0, k), w, accP);
            accQ = fmaf(__shfl(x0v0, k), w, accQ);
        }
#pragma unroll
        for (int k = 0; k < 64; ++k) {
            const float w = W1T[64 + k][lane];
            accP = fmaf(__shfl(xv1, k), w, accP);
            accQ = fmaf(__shfl(x0v1, k), w, accQ);
        }
    }
    A1[(size_t)row * 64 + lane] = accQ + b1[lane];
    U1[(size_t)row * 64 + lane] = accP - accQ;
}

// ---------------------------------------------------------------- k_mid
// per-row chain (fp32 exact): relu-JVP layer2 -> zs -> decoder 1,2 -> G2 (fp32)
__global__ __launch_bounds__(256) void k_mid(const float* __restrict__ A1,
                                             const float* __restrict__ U1,
                                             const float* __restrict__ W2,
                                             const float* __restrict__ b2,
                                             const float* __restrict__ W3,
                                             const float* __restrict__ b3,
                                             const float* __restrict__ D1,
                                             const float* __restrict__ d1,
                                             const float* __restrict__ D2,
                                             const float* __restrict__ d2,
                                             float* __restrict__ out_zs,
                                             float* __restrict__ G2) {
    __shared__ float W2T[64 * 32], W3T[32 * 32], D1T[32 * 32], D2T[32 * 64];
    __shared__ float b2f[32], b3f[32], d1f[32], d2f[64];
    const int tid = threadIdx.x;
    for (int t = tid; t < 2048; t += 256) { int o = t >> 6, k = t & 63; W2T[k * 32 + o] = W2[t]; }
    for (int t = tid; t < 1024; t += 256) { int o = t >> 5, k = t & 31; W3T[k * 32 + o] = W3[t]; }
    for (int t = tid; t < 1024; t += 256) { int o = t >> 5, k = t & 31; D1T[k * 32 + o] = D1[t]; }
    for (int t = tid; t < 2048; t += 256) { int o = t >> 5, k = t & 31; D2T[k * 64 + o] = D2[t]; }
    if (tid < 32) b2f[tid] = b2[tid];
    else if (tid < 64) b3f[tid - 32] = b3[tid - 32];
    else if (tid < 96) d1f[tid - 64] = d1[tid - 64];
    else if (tid < 160) d2f[tid - 96] = d2[tid - 96];
    __syncthreads();

    const int wave = tid >> 6, lane = tid & 63;
    const int wgid = blockIdx.x * 4 + wave;  // 0..1023
    const int o32 = lane & 31;
    for (int r = 0; r < 8; ++r) {
        const int row = wgid + r * 1024;
        const float a1 = A1[(size_t)row * 64 + lane];
        const float u1 = U1[(size_t)row * 64 + lane];
        const float h1 = fmaxf(a1, 0.f);
        const float th1 = (a1 > 0.f) ? u1 : 0.f;
        float a2 = b2f[o32], u2 = 0.f;
#pragma unroll
        for (int k = 0; k < 64; ++k) {
            const float h = __shfl(h1, k);
            const float t = __shfl(th1, k);
            const float w = W2T[k * 32 + o32];
            a2 = fmaf(h, w, a2);
            u2 = fmaf(t, w, u2);
        }
        const float s = fmaxf(a2, 0.f) + ((a2 > 0.f) ? u2 : 0.f);
        float z = b3f[o32];
#pragma unroll
        for (int k = 0; k < 32; ++k) z = fmaf(__shfl(s, k), W3T[k * 32 + o32], z);
        if (lane < 32) out_zs[(size_t)row * 32 + lane] = z;
        float g1 = d1f[o32];
#pragma unroll
        for (int k = 0; k < 32; ++k) g1 = fmaf(__shfl(z, k), D1T[k * 32 + o32], g1);
        g1 = fmaxf(g1, 0.f);
        float g2 = d2f[lane];
#pragma unroll
        for (int k = 0; k < 32; ++k) g2 = fmaf(__shfl(g1, k), D2T[k * 64 + lane], g2);
        g2 = fmaxf(g2, 0.f);
        G2[(size_t)row * 64 + lane] = g2;
    }
}

// ---------------------------------------------------------------- k_decf
// EXACT fp32: x_hats = G2 @ D3^T + d3. Wave = row, lane covers 2x64 cols.
// grid = (256 row-blocks of 32, 4 col-blocks of 128). D3 tile transposed in LDS.
__global__ __launch_bounds__(256) void k_decf(const float* __restrict__ G2,
                                              const float* __restrict__ D3,
                                              const float* __restrict__ d3,
                                              float* __restrict__ xhat) {
    __shared__ float D3T[64][128];  // 32 KB
    const int tid = threadIdx.x, wave = tid >> 6, lane = tid & 63;
    const int nbase = blockIdx.y * 128;
    const int r0 = blockIdx.x * 32;
    {   // stage D3T[k][nl] <- D3[nbase+nl][k]
        const int nl = tid >> 1;           // 0..127
        const int kb = (tid & 1) * 32;     // 0,32
        const float* src = D3 + (size_t)(nbase + nl) * 64 + kb;
#pragma unroll
        for (int i = 0; i < 32; i += 4) {
            const float4 v = *(const float4*)(src + i);
            D3T[kb + i + 0][nl] = v.x;
            D3T[kb + i + 1][nl] = v.y;
            D3T[kb + i + 2][nl] = v.z;
            D3T[kb + i + 3][nl] = v.w;
        }
    }
    __syncthreads();
    const float d3v0 = d3[nbase + lane];
    const float d3v1 = d3[nbase + 64 + lane];
    for (int rr = 0; rr < 8; ++rr) {
        const int row = r0 + wave * 8 + rr;
        const float g = G2[(size_t)row * 64 + lane];
        float acc0 = d3v0, acc1 = d3v1;
#pragma unroll
        for (int k = 0; k < 64; ++k) {
            const float gv = __shfl(g, k);
            acc0 = fmaf(gv, D3T[k][lane], acc0);
            acc1 = fmaf(gv, D3T[k][64 + lane], acc1);
        }
        xhat[(size_t)row * DIM + nbase + lane] = acc0;
        xhat[(size_t)row * DIM + nbase + 64 + lane] = acc1;
    }
}

extern "C" void kernel_launch(void* const* d_in, const int* in_sizes, int n_in,
                              void* d_out, int out_size, void* d_ws, size_t ws_size,
                              hipStream_t stream) {
    const float* xs = (const float*)d_in[0];
    const float* W1 = (const float*)d_in[1];
    const float* b1 = (const float*)d_in[2];
    const float* W2 = (const float*)d_in[3];
    const float* b2 = (const float*)d_in[4];
    const float* W3 = (const float*)d_in[5];
    const float* b3 = (const float*)d_in[6];
    const float* D1 = (const float*)d_in[7];
    const float* d1 = (const float*)d_in[8];
    const float* D2 = (const float*)d_in[9];
    const float* d2 = (const float*)d_in[10];
    const float* D3 = (const float*)d_in[11];
    const float* d3 = (const float*)d_in[12];

    // workspace layout (bytes), footprint ~16.9 MB.
    // A1/U1/G2 overlay xs_lo's region: xs_lo is dead after k_nn (stream-ordered).
    char* ws = (char*)d_ws;
    float* sq = (float*)(ws);                                     // @0        32 KB
    unsigned long long* nn = (unsigned long long*)(ws + 32768);   // @32768    64 KB
    unsigned short* xs_hi = (unsigned short*)(ws + 131072);       // @131072    8 MB
    unsigned short* xs_lo = (unsigned short*)(ws + 8519680);      // @8519680   8 MB
    float* A1 = (float*)(ws + 8519680);                           // overlays xs_lo
    float* U1 = (float*)(ws + 10616832);
    float* G2 = (float*)(ws + 12713984);
    // NOTE: A1 aliases xs_lo start; k_l1f reads only xs (fp32) + nn -> no hazard.

    float* xhat = (float*)d_out;
    float* zs = (float*)d_out + (size_t)NROWS * DIM;

    hipLaunchKernelGGL(k_split, dim3(4096), dim3(256), 0, stream, xs, xs_hi, xs_lo);
    hipLaunchKernelGGL(k_sq_init, dim3(2048), dim3(256), 0, stream, xs, sq, nn);
    hipLaunchKernelGGL(k_nn, dim3(64, 8), dim3(256), 0, stream, xs_hi, xs_lo, sq, nn);
    hipLaunchKernelGGL(k_l1f, dim3(2048), dim3(256), 0, stream, xs, nn, W1, b1, A1, U1);
    hipLaunchKernelGGL(k_mid, dim3(256), dim3(256), 0, stream, A1, U1, W2, b2, W3, b3,
                       D1, d1, D2, d2, zs, G2);
    hipLaunchKernelGGL(k_decf, dim3(256, 4), dim3(256), 0, stream, G2, D3, d3, xhat);
}

// Round 6
// 361.407 us; speedup vs baseline: 1.3513x; 1.3513x over previous
//
#include <hip/hip_runtime.h>
#include <hip/hip_bf16.h>

#define NROWS 8192
#define DIM 512
#define LST2 40  // BK=32 LDS row stride in shorts (32 data + 8 pad; rows 16B-aligned)

typedef __attribute__((ext_vector_type(8))) short bf16x8;
typedef __attribute__((ext_vector_type(4))) float f32x4;
typedef __attribute__((ext_vector_type(4))) unsigned short u16x4;
typedef __attribute__((ext_vector_type(8))) unsigned short u16x8;

__device__ __forceinline__ float bf2f(unsigned short u) {
    return __uint_as_float(((unsigned int)u) << 16);
}
__device__ __forceinline__ unsigned short f2bf(float f) {
    unsigned int b = __float_as_uint(f);
    return (unsigned short)((b + 0x7FFFu + ((b >> 16) & 1u)) >> 16);
}
// monotone float->uint key: a<b (float) <=> key(a)<key(b) (uint)
__device__ __forceinline__ unsigned int fkey(float f) {
    unsigned int b = __float_as_uint(f);
    return (b & 0x80000000u) ? ~b : (b | 0x80000000u);
}

// ---------------------------------------------------------------- k_prep
// One pass over xs: bf16 hi/lo planes + sq[row] + nn init. Wave = row.
__global__ __launch_bounds__(256) void k_prep(const float* __restrict__ xs,
                                              unsigned short* __restrict__ hi,
                                              unsigned short* __restrict__ lo,
                                              float* __restrict__ sq,
                                              unsigned long long* __restrict__ nn) {
    const int wave = threadIdx.x >> 6, lane = threadIdx.x & 63;
    const int row = blockIdx.x * 4 + wave;
    const float4* xr = (const float4*)(xs + (size_t)row * DIM);
    const float4 a = xr[2 * lane], b = xr[2 * lane + 1];  // floats lane*8..lane*8+7
    float v[8] = {a.x, a.y, a.z, a.w, b.x, b.y, b.z, b.w};
    u16x8 h, l;
    float s = 0.f;
#pragma unroll
    for (int i = 0; i < 8; ++i) {
        const unsigned short hs = f2bf(v[i]);
        h[i] = hs;
        l[i] = f2bf(v[i] - bf2f(hs));
        s = fmaf(v[i], v[i], s);
    }
    *(u16x8*)(hi + (size_t)row * DIM + lane * 8) = h;
    *(u16x8*)(lo + (size_t)row * DIM + lane * 8) = l;
#pragma unroll
    for (int d = 32; d; d >>= 1) s += __shfl_xor(s, d);
    if (lane == 0) { sq[row] = s; nn[row] = ~0ull; }
}

// ---------------------------------------------------------------- k_nn
// Triangle-scheduled fused distance + dual argmin (rows AND columns).
// grid = (64, 33): tile pair (bi, bj=(bx+by)&63); each unordered pair once
// (by==32 gives 32 benign duplicates). Split-bf16 3-MFMA, BK=32.
__global__ __launch_bounds__(256) void k_nn(const unsigned short* __restrict__ xh,
                                            const unsigned short* __restrict__ xl,
                                            const float* __restrict__ sq,
                                            unsigned long long* __restrict__ nn) {
    __shared__ __align__(16) unsigned short lAh[128 * LST2];
    __shared__ __align__(16) unsigned short lAl[128 * LST2];
    __shared__ __align__(16) unsigned short lBh[128 * LST2];
    __shared__ __align__(16) unsigned short lBl[128 * LST2];
    const int tid = threadIdx.x;
    const int wave = tid >> 6, lane = tid & 63, quad = lane >> 4, ln = lane & 15;
    const int bi = blockIdx.x, bj = (blockIdx.x + blockIdx.y) & 63;
    const int i0 = bi * 128, j0 = bj * 128;
    const int m_off = (wave & 1) * 64, n_off = (wave >> 1) * 64;

    f32x4 acc[4][4];
#pragma unroll
    for (int a = 0; a < 4; ++a)
#pragma unroll
        for (int b = 0; b < 4; ++b) acc[a][b] = (f32x4){0.f, 0.f, 0.f, 0.f};

    for (int kt = 0; kt < 16; ++kt) {
        __syncthreads();
#pragma unroll
        for (int r = 0; r < 2; ++r) {
            const int idx = r * 256 + tid;
            const int row = idx >> 2, c = idx & 3;
            const size_t ga = (size_t)(i0 + row) * DIM + kt * 32 + c * 8;
            const size_t gb = (size_t)(j0 + row) * DIM + kt * 32 + c * 8;
            *(uint4*)(lAh + row * LST2 + c * 8) = *(const uint4*)(xh + ga);
            *(uint4*)(lAl + row * LST2 + c * 8) = *(const uint4*)(xl + ga);
            *(uint4*)(lBh + row * LST2 + c * 8) = *(const uint4*)(xh + gb);
            *(uint4*)(lBl + row * LST2 + c * 8) = *(const uint4*)(xl + gb);
        }
        __syncthreads();
        bf16x8 ah[4], al[4], bh[4], bl[4];
#pragma unroll
        for (int ms = 0; ms < 4; ++ms) {
            const int row = m_off + ms * 16 + ln;
            ah[ms] = *(const bf16x8*)(lAh + row * LST2 + quad * 8);
            al[ms] = *(const bf16x8*)(lAl + row * LST2 + quad * 8);
        }
#pragma unroll
        for (int ns = 0; ns < 4; ++ns) {
            const int row = n_off + ns * 16 + ln;
            bh[ns] = *(const bf16x8*)(lBh + row * LST2 + quad * 8);
            bl[ns] = *(const bf16x8*)(lBl + row * LST2 + quad * 8);
        }
#pragma unroll
        for (int ms = 0; ms < 4; ++ms)
#pragma unroll
            for (int ns = 0; ns < 4; ++ns) {
                acc[ms][ns] = __builtin_amdgcn_mfma_f32_16x16x32_bf16(
                    ah[ms], bh[ns], acc[ms][ns], 0, 0, 0);
                acc[ms][ns] = __builtin_amdgcn_mfma_f32_16x16x32_bf16(
                    ah[ms], bl[ns], acc[ms][ns], 0, 0, 0);
                acc[ms][ns] = __builtin_amdgcn_mfma_f32_16x16x32_bf16(
                    al[ms], bh[ns], acc[ms][ns], 0, 0, 0);
            }
    }
    // ---- epilogue: dual argmin ----
    const bool diag = (i0 == j0);
    float sqj[4];
#pragma unroll
    for (int ns = 0; ns < 4; ++ns) sqj[ns] = sq[j0 + n_off + ns * 16 + ln];
    float sqi[4][4];
#pragma unroll
    for (int ms = 0; ms < 4; ++ms)
#pragma unroll
        for (int v = 0; v < 4; ++v)
            sqi[ms][v] = sq[i0 + m_off + ms * 16 + quad * 4 + v];

    // row side: for each i-row, min over the tile's 128 j (ns in-lane, ln cross-lane)
#pragma unroll
    for (int ms = 0; ms < 4; ++ms)
#pragma unroll
        for (int v = 0; v < 4; ++v) {
            const int gi = i0 + m_off + ms * 16 + quad * 4 + v;
            float mv = __builtin_inff();
            int mi = 0;
#pragma unroll
            for (int ns = 0; ns < 4; ++ns) {
                const int gj = j0 + n_off + ns * 16 + ln;
                float d2 = fmaf(-2.f, acc[ms][ns][v], sqj[ns]);
                if (diag && gj == gi) d2 = __builtin_inff();
                if (d2 < mv) { mv = d2; mi = gj; }
            }
            unsigned long long p =
                (((unsigned long long)fkey(mv)) << 32) | (unsigned int)mi;
#pragma unroll
            for (int d = 1; d < 16; d <<= 1) {
                unsigned long long o = __shfl_xor(p, d);
                p = (o < p) ? o : p;
            }
            if (ln == 0) atomicMin(&nn[gi], p);
        }
    // column side: for each j-col, min over the tile's 128 i (ms,v in-lane, quad cross)
#pragma unroll
    for (int ns = 0; ns < 4; ++ns) {
        const int gj = j0 + n_off + ns * 16 + ln;
        unsigned long long p = ~0ull;
#pragma unroll
        for (int ms = 0; ms < 4; ++ms)
#pragma unroll
            for (int v = 0; v < 4; ++v) {
                const int gi = i0 + m_off + ms * 16 + quad * 4 + v;
                const float d2 = fmaf(-2.f, acc[ms][ns][v], sqi[ms][v]);
                const unsigned long long q =
                    (((unsigned long long)fkey(d2)) << 32) | (unsigned int)gi;
                if (!(diag && gi == gj) && q < p) p = q;
            }
        {
            unsigned long long o = __shfl_xor(p, 16);
            p = (o < p) ? o : p;
            o = __shfl_xor(p, 32);
            p = (o < p) ? o : p;
        }
        if (quad == 0) atomicMin(&nn[gj], p);
    }
}

// ---------------------------------------------------------------- k_p
// EXACT fp32: P = xs @ W1^T  [8192 x 64]. 16 rows/block (4 per wave),
// W1^T k-tile [128][65] in LDS (pad 65 kills the bank-conflict storm).
__global__ __launch_bounds__(256) void k_p(const float* __restrict__ xs,
                                           const float* __restrict__ W1,
                                           float* __restrict__ P) {
    __shared__ float W1T[128][65];
    const int tid = threadIdx.x, wave = tid >> 6, lane = tid & 63;
    const int r0 = blockIdx.x * 16;
    float acc[4] = {0.f, 0.f, 0.f, 0.f};
    for (int kt = 0; kt < 4; ++kt) {
        __syncthreads();
        {   // stage W1T[kk][n] <- W1[n][kt*128+kk]
            const int n = tid >> 2;
            const int kb = (tid & 3) * 32;
            const float* src = W1 + (size_t)n * DIM + kt * 128 + kb;
#pragma unroll
            for (int i = 0; i < 32; i += 4) {
                const float4 v = *(const float4*)(src + i);
                W1T[kb + i + 0][n] = v.x;
                W1T[kb + i + 1][n] = v.y;
                W1T[kb + i + 2][n] = v.z;
                W1T[kb + i + 3][n] = v.w;
            }
        }
        __syncthreads();
        float xv0[4], xv1[4];
#pragma unroll
        for (int rr = 0; rr < 4; ++rr) {
            const int row = r0 + wave * 4 + rr;
            xv0[rr] = xs[(size_t)row * DIM + kt * 128 + lane];
            xv1[rr] = xs[(size_t)row * DIM + kt * 128 + 64 + lane];
        }
        // same fma chain order as the verified round-5 kernel (bit-identical P)
#pragma unroll
        for (int k = 0; k < 64; ++k) {
            const float w = W1T[k][lane];
#pragma unroll
            for (int rr = 0; rr < 4; ++rr)
                acc[rr] = fmaf(__shfl(xv0[rr], k), w, acc[rr]);
        }
#pragma unroll
        for (int k = 0; k < 64; ++k) {
            const float w = W1T[64 + k][lane];
#pragma unroll
            for (int rr = 0; rr < 4; ++rr)
                acc[rr] = fmaf(__shfl(xv1[rr], k), w, acc[rr]);
        }
    }
#pragma unroll
    for (int rr = 0; rr < 4; ++rr)
        P[(size_t)(r0 + wave * 4 + rr) * 64 + lane] = acc[rr];
}

// ---------------------------------------------------------------- k_mid
// per-row chain (fp32 exact). A1/U1 from P via nn gather: Q = P[nn[row]] exactly.
__global__ __launch_bounds__(256) void k_mid(const float* __restrict__ P,
                                             const unsigned long long* __restrict__ nn,
                                             const float* __restrict__ b1,
                                             const float* __restrict__ W2,
                                             const float* __restrict__ b2,
                                             const float* __restrict__ W3,
                                             const float* __restrict__ b3,
                                             const float* __restrict__ D1,
                                             const float* __restrict__ d1,
                                             const float* __restrict__ D2,
                                             const float* __restrict__ d2,
                                             float* __restrict__ out_zs,
                                             float* __restrict__ G2) {
    __shared__ float W2T[64 * 32], W3T[32 * 32], D1T[32 * 32], D2T[32 * 64];
    __shared__ float b2f[32], b3f[32], d1f[32], d2f[64];
    const int tid = threadIdx.x;
    for (int t = tid; t < 2048; t += 256) { int o = t >> 6, k = t & 63; W2T[k * 32 + o] = W2[t]; }
    for (int t = tid; t < 1024; t += 256) { int o = t >> 5, k = t & 31; W3T[k * 32 + o] = W3[t]; }
    for (int t = tid; t < 1024; t += 256) { int o = t >> 5, k = t & 31; D1T[k * 32 + o] = D1[t]; }
    for (int t = tid; t < 2048; t += 256) { int o = t >> 5, k = t & 31; D2T[k * 64 + o] = D2[t]; }
    if (tid < 32) b2f[tid] = b2[tid];
    else if (tid < 64) b3f[tid - 32] = b3[tid - 32];
    else if (tid < 96) d1f[tid - 64] = d1[tid - 64];
    else if (tid < 160) d2f[tid - 96] = d2[tid - 96];
    __syncthreads();

    const int wave = tid >> 6, lane = tid & 63;
    const int wgid = blockIdx.x * 4 + wave;  // 0..1023
    const int o32 = lane & 31;
    const float b1v = b1[lane];
    for (int r = 0; r < 8; ++r) {
        const int row = wgid + r * 1024;
        const unsigned int nnr = (unsigned int)(nn[row] & 0xFFFFFFFFull) & 8191u;
        const float pr = P[(size_t)row * 64 + lane];
        const float p0 = P[(size_t)nnr * 64 + lane];
        const float a1 = p0 + b1v;
        const float u1 = pr - p0;
        const float h1 = fmaxf(a1, 0.f);
        const float th1 = (a1 > 0.f) ? u1 : 0.f;
        float a2 = b2f[o32], u2 = 0.f;
#pragma unroll
        for (int k = 0; k < 64; ++k) {
            const float h = __shfl(h1, k);
            const float t = __shfl(th1, k);
            const float w = W2T[k * 32 + o32];
            a2 = fmaf(h, w, a2);
            u2 = fmaf(t, w, u2);
        }
        const float s = fmaxf(a2, 0.f) + ((a2 > 0.f) ? u2 : 0.f);
        float z = b3f[o32];
#pragma unroll
        for (int k = 0; k < 32; ++k) z = fmaf(__shfl(s, k), W3T[k * 32 + o32], z);
        if (lane < 32) out_zs[(size_t)row * 32 + lane] = z;
        float g1 = d1f[o32];
#pragma unroll
        for (int k = 0; k < 32; ++k) g1 = fmaf(__shfl(z, k), D1T[k * 32 + o32], g1);
        g1 = fmaxf(g1, 0.f);
        float g2 = d2f[lane];
#pragma unroll
        for (int k = 0; k < 32; ++k) g2 = fmaf(__shfl(g1, k), D2T[k * 64 + lane], g2);
        g2 = fmaxf(g2, 0.f);
        G2[(size_t)row * 64 + lane] = g2;
    }
}

// ---------------------------------------------------------------- k_decf
// EXACT fp32: x_hats = G2 @ D3^T + d3. Wave = row, lane covers 2x64 cols.
__global__ __launch_bounds__(256) void k_decf(const float* __restrict__ G2,
                                              const float* __restrict__ D3,
                                              const float* __restrict__ d3,
                                              float* __restrict__ xhat) {
    __shared__ float D3T[64][128];  // 32 KB
    const int tid = threadIdx.x, wave = tid >> 6, lane = tid & 63;
    const int nbase = blockIdx.y * 128;
    const int r0 = blockIdx.x * 32;
    {   // stage D3T[k][nl] <- D3[nbase+nl][k]
        const int nl = tid >> 1;           // 0..127
        const int kb = (tid & 1) * 32;     // 0,32
        const float* src = D3 + (size_t)(nbase + nl) * 64 + kb;
#pragma unroll
        for (int i = 0; i < 32; i += 4) {
            const float4 v = *(const float4*)(src + i);
            D3T[kb + i + 0][nl] = v.x;
            D3T[kb + i + 1][nl] = v.y;
            D3T[kb + i + 2][nl] = v.z;
            D3T[kb + i + 3][nl] = v.w;
        }
    }
    __syncthreads();
    const float d3v0 = d3[nbase + lane];
    const float d3v1 = d3[nbase + 64 + lane];
    for (int rr = 0; rr < 8; ++rr) {
        const int row = r0 + wave * 8 + rr;
        const float g = G2[(size_t)row * 64 + lane];
        float acc0 = d3v0, acc1 = d3v1;
#pragma unroll
        for (int k = 0; k < 64; ++k) {
            const float gv = __shfl(g, k);
            acc0 = fmaf(gv, D3T[k][lane], acc0);
            acc1 = fmaf(gv, D3T[k][64 + lane], acc1);
        }
        xhat[(size_t)row * DIM + nbase + lane] = acc0;
        xhat[(size_t)row * DIM + nbase + 64 + lane] = acc1;
    }
}

extern "C" void kernel_launch(void* const* d_in, const int* in_sizes, int n_in,
                              void* d_out, int out_size, void* d_ws, size_t ws_size,
                              hipStream_t stream) {
    const float* xs = (const float*)d_in[0];
    const float* W1 = (const float*)d_in[1];
    const float* b1 = (const float*)d_in[2];
    const float* W2 = (const float*)d_in[3];
    const float* b2 = (const float*)d_in[4];
    const float* W3 = (const float*)d_in[5];
    const float* b3 = (const float*)d_in[6];
    const float* D1 = (const float*)d_in[7];
    const float* d1 = (const float*)d_in[8];
    const float* D2 = (const float*)d_in[9];
    const float* d2 = (const float*)d_in[10];
    const float* D3 = (const float*)d_in[11];
    const float* d3 = (const float*)d_in[12];

    // workspace: sq | nn | xs_hi | xs_lo(dead after k_nn; P,G2 overlay it)
    char* ws = (char*)d_ws;
    float* sq = (float*)(ws);                                     // @0        32 KB
    unsigned long long* nn = (unsigned long long*)(ws + 32768);   // @32768    64 KB
    unsigned short* xs_hi = (unsigned short*)(ws + 131072);       // @131072    8 MB
    unsigned short* xs_lo = (unsigned short*)(ws + 8519680);      // @8519680   8 MB
    float* P = (float*)(ws + 8519680);                            // overlays xs_lo
    float* G2 = (float*)(ws + 10616832);                          // +2 MB

    float* xhat = (float*)d_out;
    float* zs = (float*)d_out + (size_t)NROWS * DIM;

    hipLaunchKernelGGL(k_prep, dim3(2048), dim3(256), 0, stream, xs, xs_hi, xs_lo, sq, nn);
    hipLaunchKernelGGL(k_nn, dim3(64, 33), dim3(256), 0, stream, xs_hi, xs_lo, sq, nn);
    hipLaunchKernelGGL(k_p, dim3(512), dim3(256), 0, stream, xs, W1, P);
    hipLaunchKernelGGL(k_mid, dim3(256), dim3(256), 0, stream, P, nn, b1, W2, b2, W3, b3,
                       D1, d1, D2, d2, zs, G2);
    hipLaunchKernelGGL(k_decf, dim3(256, 4), dim3(256), 0, stream, G2, D3, d3, xhat);
}

// Round 7
// 330.787 us; speedup vs baseline: 1.4764x; 1.0926x over previous
//
#include <hip/hip_runtime.h>
#include <hip/hip_bf16.h>

#define NROWS 8192
#define DIM 512

typedef __attribute__((ext_vector_type(8))) short bf16x8;
typedef __attribute__((ext_vector_type(4))) float f32x4;
typedef __attribute__((ext_vector_type(8))) unsigned short u16x8;

__device__ __forceinline__ float bf2f(unsigned short u) {
    return __uint_as_float(((unsigned int)u) << 16);
}
__device__ __forceinline__ unsigned short f2bf(float f) {
    unsigned int b = __float_as_uint(f);
    return (unsigned short)((b + 0x7FFFu + ((b >> 16) & 1u)) >> 16);
}
// monotone float->uint key: a<b (float) <=> key(a)<key(b) (uint)
__device__ __forceinline__ unsigned int fkey(float f) {
    unsigned int b = __float_as_uint(f);
    return (b & 0x80000000u) ? ~b : (b | 0x80000000u);
}

// ---------------------------------------------------------------- k_prep
// One pass over xs: bf16 hi/lo planes + sq[row] + nn init. Wave = row.
__global__ __launch_bounds__(256) void k_prep(const float* __restrict__ xs,
                                              unsigned short* __restrict__ hi,
                                              unsigned short* __restrict__ lo,
                                              float* __restrict__ sq,
                                              unsigned long long* __restrict__ nn) {
    const int wave = threadIdx.x >> 6, lane = threadIdx.x & 63;
    const int row = blockIdx.x * 4 + wave;
    const float4* xr = (const float4*)(xs + (size_t)row * DIM);
    const float4 a = xr[2 * lane], b = xr[2 * lane + 1];
    float v[8] = {a.x, a.y, a.z, a.w, b.x, b.y, b.z, b.w};
    u16x8 h, l;
    float s = 0.f;
#pragma unroll
    for (int i = 0; i < 8; ++i) {
        const unsigned short hs = f2bf(v[i]);
        h[i] = hs;
        l[i] = f2bf(v[i] - bf2f(hs));
        s = fmaf(v[i], v[i], s);
    }
    *(u16x8*)(hi + (size_t)row * DIM + lane * 8) = h;
    *(u16x8*)(lo + (size_t)row * DIM + lane * 8) = l;
#pragma unroll
    for (int d = 32; d; d >>= 1) s += __shfl_xor(s, d);
    if (lane == 0) { sq[row] = s; nn[row] = ~0ull; }
}

// ---------------------------------------------------------------- k_nn
// Triangle pair-space, XCD-supertiled 1D grid of 2112 blocks:
//   xcd=b&7 owns bi in [8*xcd, 8*xcd+8) (A set = 2MB, L2-resident);
//   within XCD: bi fastest, s slow -> B-tile set shifts 1 tile per s-step.
// Split-bf16 (hi/lo) 3-MFMA, BK=32, swizzled LDS (LST=32, pos=(c+(row>>1))&3:
// minimal 2-way banking on both write and read phases), register prefetch of
// the next K-slab across the MFMA section. Dual (row+col) argmin epilogue.
__global__ __launch_bounds__(256) void k_nn(const unsigned short* __restrict__ xh,
                                            const unsigned short* __restrict__ xl,
                                            const float* __restrict__ sq,
                                            unsigned long long* __restrict__ nn) {
    __shared__ __align__(16) unsigned short lAh[128 * 32];
    __shared__ __align__(16) unsigned short lAl[128 * 32];
    __shared__ __align__(16) unsigned short lBh[128 * 32];
    __shared__ __align__(16) unsigned short lBl[128 * 32];
    const int tid = threadIdx.x;
    const int wave = tid >> 6, lane = tid & 63, quad = lane >> 4, ln = lane & 15;
    const int b = blockIdx.x;
    const int xcd = b & 7, w = b >> 3;
    const int s = w >> 3, bil = w & 7;
    const int bi = xcd * 8 + bil;
    const int bj = (bi + s) & 63;
    const int i0 = bi * 128, j0 = bj * 128;
    const int m_off = (wave & 1) * 64, n_off = (wave >> 1) * 64;

    // staging: thread covers chunks (row0,c0) and (row1,c0); addresses constant
    const int row0 = tid >> 2, c0 = tid & 3;
    const int row1 = 64 + row0;
    const size_t gA0 = (size_t)(i0 + row0) * DIM + c0 * 8;
    const size_t gA1 = (size_t)(i0 + row1) * DIM + c0 * 8;
    const size_t gB0 = (size_t)(j0 + row0) * DIM + c0 * 8;
    const size_t gB1 = (size_t)(j0 + row1) * DIM + c0 * 8;
    const int w0 = row0 * 32 + ((c0 + (row0 >> 1)) & 3) * 8;  // shorts
    const int w1 = row1 * 32 + ((c0 + (row1 >> 1)) & 3) * 8;

    // fragment read offsets (shorts), constant across kt
    int aoff[4], boff[4];
#pragma unroll
    for (int ms = 0; ms < 4; ++ms) {
        const int r = m_off + ms * 16 + ln;
        aoff[ms] = r * 32 + ((quad + (r >> 1)) & 3) * 8;
    }
#pragma unroll
    for (int ns = 0; ns < 4; ++ns) {
        const int r = n_off + ns * 16 + ln;
        boff[ns] = r * 32 + ((quad + (r >> 1)) & 3) * 8;
    }

    f32x4 acc[4][4];
#pragma unroll
    for (int a = 0; a < 4; ++a)
#pragma unroll
        for (int c = 0; c < 4; ++c) acc[a][c] = (f32x4){0.f, 0.f, 0.f, 0.f};

    // prefetch kt=0
    uint4 vAh0 = *(const uint4*)(xh + gA0), vAh1 = *(const uint4*)(xh + gA1);
    uint4 vAl0 = *(const uint4*)(xl + gA0), vAl1 = *(const uint4*)(xl + gA1);
    uint4 vBh0 = *(const uint4*)(xh + gB0), vBh1 = *(const uint4*)(xh + gB1);
    uint4 vBl0 = *(const uint4*)(xl + gB0), vBl1 = *(const uint4*)(xl + gB1);

    for (int kt = 0; kt < 16; ++kt) {
        __syncthreads();
        *(uint4*)(lAh + w0) = vAh0; *(uint4*)(lAh + w1) = vAh1;
        *(uint4*)(lAl + w0) = vAl0; *(uint4*)(lAl + w1) = vAl1;
        *(uint4*)(lBh + w0) = vBh0; *(uint4*)(lBh + w1) = vBh1;
        *(uint4*)(lBl + w0) = vBl0; *(uint4*)(lBl + w1) = vBl1;
        if (kt < 15) {  // issue next slab; lands during the MFMA section
            const size_t ko = (size_t)(kt + 1) * 32;
            vAh0 = *(const uint4*)(xh + gA0 + ko); vAh1 = *(const uint4*)(xh + gA1 + ko);
            vAl0 = *(const uint4*)(xl + gA0 + ko); vAl1 = *(const uint4*)(xl + gA1 + ko);
            vBh0 = *(const uint4*)(xh + gB0 + ko); vBh1 = *(const uint4*)(xh + gB1 + ko);
            vBl0 = *(const uint4*)(xl + gB0 + ko); vBl1 = *(const uint4*)(xl + gB1 + ko);
        }
        __syncthreads();
        bf16x8 ah[4], al[4], bh[4], bl[4];
#pragma unroll
        for (int ms = 0; ms < 4; ++ms) {
            ah[ms] = *(const bf16x8*)(lAh + aoff[ms]);
            al[ms] = *(const bf16x8*)(lAl + aoff[ms]);
        }
#pragma unroll
        for (int ns = 0; ns < 4; ++ns) {
            bh[ns] = *(const bf16x8*)(lBh + boff[ns]);
            bl[ns] = *(const bf16x8*)(lBl + boff[ns]);
        }
#pragma unroll
        for (int ms = 0; ms < 4; ++ms)
#pragma unroll
            for (int ns = 0; ns < 4; ++ns) {
                acc[ms][ns] = __builtin_amdgcn_mfma_f32_16x16x32_bf16(
                    ah[ms], bh[ns], acc[ms][ns], 0, 0, 0);
                acc[ms][ns] = __builtin_amdgcn_mfma_f32_16x16x32_bf16(
                    ah[ms], bl[ns], acc[ms][ns], 0, 0, 0);
                acc[ms][ns] = __builtin_amdgcn_mfma_f32_16x16x32_bf16(
                    al[ms], bh[ns], acc[ms][ns], 0, 0, 0);
            }
    }
    // ---- epilogue: dual argmin ----
    const bool diag = (i0 == j0);
    float sqj[4];
#pragma unroll
    for (int ns = 0; ns < 4; ++ns) sqj[ns] = sq[j0 + n_off + ns * 16 + ln];
    float sqi[4][4];
#pragma unroll
    for (int ms = 0; ms < 4; ++ms)
#pragma unroll
        for (int v = 0; v < 4; ++v)
            sqi[ms][v] = sq[i0 + m_off + ms * 16 + quad * 4 + v];

    // row side: per i-row, min over this tile's 128 j
#pragma unroll
    for (int ms = 0; ms < 4; ++ms)
#pragma unroll
        for (int v = 0; v < 4; ++v) {
            const int gi = i0 + m_off + ms * 16 + quad * 4 + v;
            float mv = __builtin_inff();
            int mi = 0;
#pragma unroll
            for (int ns = 0; ns < 4; ++ns) {
                const int gj = j0 + n_off + ns * 16 + ln;
                float d2 = fmaf(-2.f, acc[ms][ns][v], sqj[ns]);
                if (diag && gj == gi) d2 = __builtin_inff();
                if (d2 < mv) { mv = d2; mi = gj; }
            }
            unsigned long long p =
                (((unsigned long long)fkey(mv)) << 32) | (unsigned int)mi;
#pragma unroll
            for (int d = 1; d < 16; d <<= 1) {
                unsigned long long o = __shfl_xor(p, d);
                p = (o < p) ? o : p;
            }
            if (ln == 0) atomicMin(&nn[gi], p);
        }
    // column side: per j-col, min over this tile's 128 i
#pragma unroll
    for (int ns = 0; ns < 4; ++ns) {
        const int gj = j0 + n_off + ns * 16 + ln;
        unsigned long long p = ~0ull;
#pragma unroll
        for (int ms = 0; ms < 4; ++ms)
#pragma unroll
            for (int v = 0; v < 4; ++v) {
                const int gi = i0 + m_off + ms * 16 + quad * 4 + v;
                const float d2 = fmaf(-2.f, acc[ms][ns][v], sqi[ms][v]);
                const unsigned long long q =
                    (((unsigned long long)fkey(d2)) << 32) | (unsigned int)gi;
                if (!(diag && gi == gj) && q < p) p = q;
            }
        {
            unsigned long long o = __shfl_xor(p, 16);
            p = (o < p) ? o : p;
            o = __shfl_xor(p, 32);
            p = (o < p) ? o : p;
        }
        if (quad == 0) atomicMin(&nn[gj], p);
    }
}

// ---------------------------------------------------------------- k_p
// EXACT fp32: P = xs @ W1^T  [8192 x 64]. 16 rows/block (4 per wave),
// W1^T k-tile [128][65] in LDS.
__global__ __launch_bounds__(256) void k_p(const float* __restrict__ xs,
                                           const float* __restrict__ W1,
                                           float* __restrict__ P) {
    __shared__ float W1T[128][65];
    const int tid = threadIdx.x, wave = tid >> 6, lane = tid & 63;
    const int r0 = blockIdx.x * 16;
    float acc[4] = {0.f, 0.f, 0.f, 0.f};
    for (int kt = 0; kt < 4; ++kt) {
        __syncthreads();
        {
            const int n = tid >> 2;
            const int kb = (tid & 3) * 32;
            const float* src = W1 + (size_t)n * DIM + kt * 128 + kb;
#pragma unroll
            for (int i = 0; i < 32; i += 4) {
                const float4 v = *(const float4*)(src + i);
                W1T[kb + i + 0][n] = v.x;
                W1T[kb + i + 1][n] = v.y;
                W1T[kb + i + 2][n] = v.z;
                W1T[kb + i + 3][n] = v.w;
            }
        }
        __syncthreads();
        float xv0[4], xv1[4];
#pragma unroll
        for (int rr = 0; rr < 4; ++rr) {
            const int row = r0 + wave * 4 + rr;
            xv0[rr] = xs[(size_t)row * DIM + kt * 128 + lane];
            xv1[rr] = xs[(size_t)row * DIM + kt * 128 + 64 + lane];
        }
#pragma unroll
        for (int k = 0; k < 64; ++k) {
            const float w = W1T[k][lane];
#pragma unroll
            for (int rr = 0; rr < 4; ++rr)
                acc[rr] = fmaf(__shfl(xv0[rr], k), w, acc[rr]);
        }
#pragma unroll
        for (int k = 0; k < 64; ++k) {
            const float w = W1T[64 + k][lane];
#pragma unroll
            for (int rr = 0; rr < 4; ++rr)
                acc[rr] = fmaf(__shfl(xv1[rr], k), w, acc[rr]);
        }
    }
#pragma unroll
    for (int rr = 0; rr < 4; ++rr)
        P[(size_t)(r0 + wave * 4 + rr) * 64 + lane] = acc[rr];
}

// ---------------------------------------------------------------- k_mid
// per-row chain (fp32 exact). Q = P[nn[row]] exactly. grid 1024 (2 rows/wave).
__global__ __launch_bounds__(256) void k_mid(const float* __restrict__ P,
                                             const unsigned long long* __restrict__ nn,
                                             const float* __restrict__ b1,
                                             const float* __restrict__ W2,
                                             const float* __restrict__ b2,
                                             const float* __restrict__ W3,
                                             const float* __restrict__ b3,
                                             const float* __restrict__ D1,
                                             const float* __restrict__ d1,
                                             const float* __restrict__ D2,
                                             const float* __restrict__ d2,
                                             float* __restrict__ out_zs,
                                             float* __restrict__ G2) {
    __shared__ float W2T[64 * 32], W3T[32 * 32], D1T[32 * 32], D2T[32 * 64];
    __shared__ float b2f[32], b3f[32], d1f[32], d2f[64];
    const int tid = threadIdx.x;
    for (int t = tid; t < 2048; t += 256) { int o = t >> 6, k = t & 63; W2T[k * 32 + o] = W2[t]; }
    for (int t = tid; t < 1024; t += 256) { int o = t >> 5, k = t & 31; W3T[k * 32 + o] = W3[t]; }
    for (int t = tid; t < 1024; t += 256) { int o = t >> 5, k = t & 31; D1T[k * 32 + o] = D1[t]; }
    for (int t = tid; t < 2048; t += 256) { int o = t >> 5, k = t & 31; D2T[k * 64 + o] = D2[t]; }
    if (tid < 32) b2f[tid] = b2[tid];
    else if (tid < 64) b3f[tid - 32] = b3[tid - 32];
    else if (tid < 96) d1f[tid - 64] = d1[tid - 64];
    else if (tid < 160) d2f[tid - 96] = d2[tid - 96];
    __syncthreads();

    const int wave = tid >> 6, lane = tid & 63;
    const int wgid = blockIdx.x * 4 + wave;  // 0..4095
    const int o32 = lane & 31;
    const float b1v = b1[lane];
    for (int r = 0; r < 2; ++r) {
        const int row = wgid + r * 4096;
        const unsigned int nnr = (unsigned int)(nn[row] & 0xFFFFFFFFull) & 8191u;
        const float pr = P[(size_t)row * 64 + lane];
        const float p0 = P[(size_t)nnr * 64 + lane];
        const float a1 = p0 + b1v;
        const float u1 = pr - p0;
        const float h1 = fmaxf(a1, 0.f);
        const float th1 = (a1 > 0.f) ? u1 : 0.f;
        float a2 = b2f[o32], u2 = 0.f;
#pragma unroll
        for (int k = 0; k < 64; ++k) {
            const float h = __shfl(h1, k);
            const float t = __shfl(th1, k);
            const float w = W2T[k * 32 + o32];
            a2 = fmaf(h, w, a2);
            u2 = fmaf(t, w, u2);
        }
        const float s = fmaxf(a2, 0.f) + ((a2 > 0.f) ? u2 : 0.f);
        float z = b3f[o32];
#pragma unroll
        for (int k = 0; k < 32; ++k) z = fmaf(__shfl(s, k), W3T[k * 32 + o32], z);
        if (lane < 32) out_zs[(size_t)row * 32 + lane] = z;
        float g1 = d1f[o32];
#pragma unroll
        for (int k = 0; k < 32; ++k) g1 = fmaf(__shfl(z, k), D1T[k * 32 + o32], g1);
        g1 = fmaxf(g1, 0.f);
        float g2 = d2f[lane];
#pragma unroll
        for (int k = 0; k < 32; ++k) g2 = fmaf(__shfl(g1, k), D2T[k * 64 + lane], g2);
        g2 = fmaxf(g2, 0.f);
        G2[(size_t)row * 64 + lane] = g2;
    }
}

// ---------------------------------------------------------------- k_decf
// EXACT fp32: x_hats = G2 @ D3^T + d3. Wave = row, lane covers 2x64 cols.
__global__ __launch_bounds__(256) void k_decf(const float* __restrict__ G2,
                                              const float* __restrict__ D3,
                                              const float* __restrict__ d3,
                                              float* __restrict__ xhat) {
    __shared__ float D3T[64][128];  // 32 KB
    const int tid = threadIdx.x, wave = tid >> 6, lane = tid & 63;
    const int nbase = blockIdx.y * 128;
    const int r0 = blockIdx.x * 32;
    {
        const int nl = tid >> 1;
        const int kb = (tid & 1) * 32;
        const float* src = D3 + (size_t)(nbase + nl) * 64 + kb;
#pragma unroll
        for (int i = 0; i < 32; i += 4) {
            const float4 v = *(const float4*)(src + i);
            D3T[kb + i + 0][nl] = v.x;
            D3T[kb + i + 1][nl] = v.y;
            D3T[kb + i + 2][nl] = v.z;
            D3T[kb + i + 3][nl] = v.w;
        }
    }
    __syncthreads();
    const float d3v0 = d3[nbase + lane];
    const float d3v1 = d3[nbase + 64 + lane];
    for (int rr = 0; rr < 8; ++rr) {
        const int row = r0 + wave * 8 + rr;
        const float g = G2[(size_t)row * 64 + lane];
        float acc0 = d3v0, acc1 = d3v1;
#pragma unroll
        for (int k = 0; k < 64; ++k) {
            const float gv = __shfl(g, k);
            acc0 = fmaf(gv, D3T[k][lane], acc0);
            acc1 = fmaf(gv, D3T[k][64 + lane], acc1);
        }
        xhat[(size_t)row * DIM + nbase + lane] = acc0;
        xhat[(size_t)row * DIM + nbase + 64 + lane] = acc1;
    }
}

extern "C" void kernel_launch(void* const* d_in, const int* in_sizes, int n_in,
                              void* d_out, int out_size, void* d_ws, size_t ws_size,
                              hipStream_t stream) {
    const float* xs = (const float*)d_in[0];
    const float* W1 = (const float*)d_in[1];
    const float* b1 = (const float*)d_in[2];
    const float* W2 = (const float*)d_in[3];
    const float* b2 = (const float*)d_in[4];
    const float* W3 = (const float*)d_in[5];
    const float* b3 = (const float*)d_in[6];
    const float* D1 = (const float*)d_in[7];
    const float* d1 = (const float*)d_in[8];
    const float* D2 = (const float*)d_in[9];
    const float* d2 = (const float*)d_in[10];
    const float* D3 = (const float*)d_in[11];
    const float* d3 = (const float*)d_in[12];

    // workspace: sq | nn | xs_hi | xs_lo(dead after k_nn; P,G2 overlay it)
    char* ws = (char*)d_ws;
    float* sq = (float*)(ws);                                     // @0        32 KB
    unsigned long long* nn = (unsigned long long*)(ws + 32768);   // @32768    64 KB
    unsigned short* xs_hi = (unsigned short*)(ws + 131072);       // @131072    8 MB
    unsigned short* xs_lo = (unsigned short*)(ws + 8519680);      // @8519680   8 MB
    float* P = (float*)(ws + 8519680);                            // overlays xs_lo
    float* G2 = (float*)(ws + 10616832);                          // +2 MB

    float* xhat = (float*)d_out;
    float* zs = (float*)d_out + (size_t)NROWS * DIM;

    hipLaunchKernelGGL(k_prep, dim3(2048), dim3(256), 0, stream, xs, xs_hi, xs_lo, sq, nn);
    hipLaunchKernelGGL(k_nn, dim3(2112), dim3(256), 0, stream, xs_hi, xs_lo, sq, nn);
    hipLaunchKernelGGL(k_p, dim3(512), dim3(256), 0, stream, xs, W1, P);
    hipLaunchKernelGGL(k_mid, dim3(1024), dim3(256), 0, stream, P, nn, b1, W2, b2, W3, b3,
                       D1, d1, D2, d2, zs, G2);
    hipLaunchKernelGGL(k_decf, dim3(256, 4), dim3(256), 0, stream, G2, D3, d3, xhat);
}

// Round 8
// 320.842 us; speedup vs baseline: 1.5222x; 1.0310x over previous
//
#include <hip/hip_runtime.h>
#include <hip/hip_bf16.h>

#define NROWS 8192
#define DIM 512

typedef __attribute__((ext_vector_type(8))) short bf16x8;
typedef __attribute__((ext_vector_type(4))) float f32x4;
typedef __attribute__((ext_vector_type(8))) unsigned short u16x8;

__device__ __forceinline__ float bf2f(unsigned short u) {
    return __uint_as_float(((unsigned int)u) << 16);
}
__device__ __forceinline__ unsigned short f2bf(float f) {
    unsigned int b = __float_as_uint(f);
    return (unsigned short)((b + 0x7FFFu + ((b >> 16) & 1u)) >> 16);
}
// monotone float->uint key
__device__ __forceinline__ unsigned int fkey(float f) {
    unsigned int b = __float_as_uint(f);
    return (b & 0x80000000u) ? ~b : (b | 0x80000000u);
}

// ---------------------------------------------------------------- k_prep
// One pass over xs: bf16 hi/mid planes + sq[row] + nn init. Wave = row.
__global__ __launch_bounds__(256) void k_prep(const float* __restrict__ xs,
                                              unsigned short* __restrict__ hi,
                                              unsigned short* __restrict__ mo,
                                              float* __restrict__ sq,
                                              unsigned long long* __restrict__ nn) {
    const int wave = threadIdx.x >> 6, lane = threadIdx.x & 63;
    const int row = blockIdx.x * 4 + wave;
    const float4* xr = (const float4*)(xs + (size_t)row * DIM);
    const float4 a = xr[2 * lane], b = xr[2 * lane + 1];
    float v[8] = {a.x, a.y, a.z, a.w, b.x, b.y, b.z, b.w};
    u16x8 h, l;
    float s = 0.f;
#pragma unroll
    for (int i = 0; i < 8; ++i) {
        const unsigned short hs = f2bf(v[i]);
        h[i] = hs;
        l[i] = f2bf(v[i] - bf2f(hs));
        s = fmaf(v[i], v[i], s);
    }
    *(u16x8*)(hi + (size_t)row * DIM + lane * 8) = h;
    *(u16x8*)(mo + (size_t)row * DIM + lane * 8) = l;
#pragma unroll
    for (int d = 32; d; d >>= 1) s += __shfl_xor(s, d);
    if (lane == 0) { sq[row] = s; nn[row] = ~0ull; }
}

// ---------------------------------------------------------------- k_nn  (unchanged from R7)
__global__ __launch_bounds__(256) void k_nn(const unsigned short* __restrict__ xh,
                                            const unsigned short* __restrict__ xl,
                                            const float* __restrict__ sq,
                                            unsigned long long* __restrict__ nn) {
    __shared__ __align__(16) unsigned short lAh[128 * 32];
    __shared__ __align__(16) unsigned short lAl[128 * 32];
    __shared__ __align__(16) unsigned short lBh[128 * 32];
    __shared__ __align__(16) unsigned short lBl[128 * 32];
    const int tid = threadIdx.x;
    const int wave = tid >> 6, lane = tid & 63, quad = lane >> 4, ln = lane & 15;
    const int b = blockIdx.x;
    const int xcd = b & 7, w = b >> 3;
    const int s = w >> 3, bil = w & 7;
    const int bi = xcd * 8 + bil;
    const int bj = (bi + s) & 63;
    const int i0 = bi * 128, j0 = bj * 128;
    const int m_off = (wave & 1) * 64, n_off = (wave >> 1) * 64;

    const int row0 = tid >> 2, c0 = tid & 3;
    const int row1 = 64 + row0;
    const size_t gA0 = (size_t)(i0 + row0) * DIM + c0 * 8;
    const size_t gA1 = (size_t)(i0 + row1) * DIM + c0 * 8;
    const size_t gB0 = (size_t)(j0 + row0) * DIM + c0 * 8;
    const size_t gB1 = (size_t)(j0 + row1) * DIM + c0 * 8;
    const int w0 = row0 * 32 + ((c0 + (row0 >> 1)) & 3) * 8;
    const int w1 = row1 * 32 + ((c0 + (row1 >> 1)) & 3) * 8;

    int aoff[4], boff[4];
#pragma unroll
    for (int ms = 0; ms < 4; ++ms) {
        const int r = m_off + ms * 16 + ln;
        aoff[ms] = r * 32 + ((quad + (r >> 1)) & 3) * 8;
    }
#pragma unroll
    for (int ns = 0; ns < 4; ++ns) {
        const int r = n_off + ns * 16 + ln;
        boff[ns] = r * 32 + ((quad + (r >> 1)) & 3) * 8;
    }

    f32x4 acc[4][4];
#pragma unroll
    for (int a = 0; a < 4; ++a)
#pragma unroll
        for (int c = 0; c < 4; ++c) acc[a][c] = (f32x4){0.f, 0.f, 0.f, 0.f};

    uint4 vAh0 = *(const uint4*)(xh + gA0), vAh1 = *(const uint4*)(xh + gA1);
    uint4 vAl0 = *(const uint4*)(xl + gA0), vAl1 = *(const uint4*)(xl + gA1);
    uint4 vBh0 = *(const uint4*)(xh + gB0), vBh1 = *(const uint4*)(xh + gB1);
    uint4 vBl0 = *(const uint4*)(xl + gB0), vBl1 = *(const uint4*)(xl + gB1);

    for (int kt = 0; kt < 16; ++kt) {
        __syncthreads();
        *(uint4*)(lAh + w0) = vAh0; *(uint4*)(lAh + w1) = vAh1;
        *(uint4*)(lAl + w0) = vAl0; *(uint4*)(lAl + w1) = vAl1;
        *(uint4*)(lBh + w0) = vBh0; *(uint4*)(lBh + w1) = vBh1;
        *(uint4*)(lBl + w0) = vBl0; *(uint4*)(lBl + w1) = vBl1;
        if (kt < 15) {
            const size_t ko = (size_t)(kt + 1) * 32;
            vAh0 = *(const uint4*)(xh + gA0 + ko); vAh1 = *(const uint4*)(xh + gA1 + ko);
            vAl0 = *(const uint4*)(xl + gA0 + ko); vAl1 = *(const uint4*)(xl + gA1 + ko);
            vBh0 = *(const uint4*)(xh + gB0 + ko); vBh1 = *(const uint4*)(xh + gB1 + ko);
            vBl0 = *(const uint4*)(xl + gB0 + ko); vBl1 = *(const uint4*)(xl + gB1 + ko);
        }
        __syncthreads();
        bf16x8 ah[4], al[4], bh[4], bl[4];
#pragma unroll
        for (int ms = 0; ms < 4; ++ms) {
            ah[ms] = *(const bf16x8*)(lAh + aoff[ms]);
            al[ms] = *(const bf16x8*)(lAl + aoff[ms]);
        }
#pragma unroll
        for (int ns = 0; ns < 4; ++ns) {
            bh[ns] = *(const bf16x8*)(lBh + boff[ns]);
            bl[ns] = *(const bf16x8*)(lBl + boff[ns]);
        }
#pragma unroll
        for (int ms = 0; ms < 4; ++ms)
#pragma unroll
            for (int ns = 0; ns < 4; ++ns) {
                acc[ms][ns] = __builtin_amdgcn_mfma_f32_16x16x32_bf16(
                    ah[ms], bh[ns], acc[ms][ns], 0, 0, 0);
                acc[ms][ns] = __builtin_amdgcn_mfma_f32_16x16x32_bf16(
                    ah[ms], bl[ns], acc[ms][ns], 0, 0, 0);
                acc[ms][ns] = __builtin_amdgcn_mfma_f32_16x16x32_bf16(
                    al[ms], bh[ns], acc[ms][ns], 0, 0, 0);
            }
    }
    const bool diag = (i0 == j0);
    float sqj[4];
#pragma unroll
    for (int ns = 0; ns < 4; ++ns) sqj[ns] = sq[j0 + n_off + ns * 16 + ln];
    float sqi[4][4];
#pragma unroll
    for (int ms = 0; ms < 4; ++ms)
#pragma unroll
        for (int v = 0; v < 4; ++v)
            sqi[ms][v] = sq[i0 + m_off + ms * 16 + quad * 4 + v];

#pragma unroll
    for (int ms = 0; ms < 4; ++ms)
#pragma unroll
        for (int v = 0; v < 4; ++v) {
            const int gi = i0 + m_off + ms * 16 + quad * 4 + v;
            float mv = __builtin_inff();
            int mi = 0;
#pragma unroll
            for (int ns = 0; ns < 4; ++ns) {
                const int gj = j0 + n_off + ns * 16 + ln;
                float d2 = fmaf(-2.f, acc[ms][ns][v], sqj[ns]);
                if (diag && gj == gi) d2 = __builtin_inff();
                if (d2 < mv) { mv = d2; mi = gj; }
            }
            unsigned long long p =
                (((unsigned long long)fkey(mv)) << 32) | (unsigned int)mi;
#pragma unroll
            for (int d = 1; d < 16; d <<= 1) {
                unsigned long long o = __shfl_xor(p, d);
                p = (o < p) ? o : p;
            }
            if (ln == 0) atomicMin(&nn[gi], p);
        }
#pragma unroll
    for (int ns = 0; ns < 4; ++ns) {
        const int gj = j0 + n_off + ns * 16 + ln;
        unsigned long long p = ~0ull;
#pragma unroll
        for (int ms = 0; ms < 4; ++ms)
#pragma unroll
            for (int v = 0; v < 4; ++v) {
                const int gi = i0 + m_off + ms * 16 + quad * 4 + v;
                const float d2 = fmaf(-2.f, acc[ms][ns][v], sqi[ms][v]);
                const unsigned long long q =
                    (((unsigned long long)fkey(d2)) << 32) | (unsigned int)gi;
                if (!(diag && gi == gj) && q < p) p = q;
            }
        {
            unsigned long long o = __shfl_xor(p, 16);
            p = (o < p) ? o : p;
            o = __shfl_xor(p, 32);
            p = (o < p) ? o : p;
        }
        if (quad == 0) atomicMin(&nn[gj], p);
    }
}

// helper: 3-way bf16 split of 8 fp32 (h+m+l covers 24 mantissa bits)
__device__ __forceinline__ void split3(const float* v, u16x8& h8, u16x8& m8, u16x8& l8) {
#pragma unroll
    for (int j = 0; j < 8; ++j) {
        const float x = v[j];
        const unsigned short h = f2bf(x);
        const float r1 = x - bf2f(h);
        const unsigned short m = f2bf(r1);
        const float r2 = r1 - bf2f(m);
        h8[j] = h; m8[j] = m; l8[j] = f2bf(r2);
    }
}
// helper: 2-way split (16 mantissa bits + exact cross terms)
__device__ __forceinline__ void split2(const float* v, u16x8& h8, u16x8& l8) {
#pragma unroll
    for (int j = 0; j < 8; ++j) {
        const float x = v[j];
        const unsigned short h = f2bf(x);
        h8[j] = h; l8[j] = f2bf(x - bf2f(h));
    }
}

// ---------------------------------------------------------------- k_p
// P = xs @ W1^T via 3-way-split bf16 MFMA (6 products -> ~fp32 accuracy,
// gate-safe). Block = 64 rows x 64 cols, K=512 in 16 steps. 128 blocks.
__global__ __launch_bounds__(256) void k_p(const float* __restrict__ xs,
                                           const float* __restrict__ W1,
                                           float* __restrict__ P) {
    __shared__ __align__(16) unsigned short lAh[64 * 32], lAm[64 * 32], lAl[64 * 32];
    __shared__ __align__(16) unsigned short lWh[64 * 32], lWm[64 * 32], lWl[64 * 32];
    const int tid = threadIdx.x, wave = tid >> 6, lane = tid & 63, quad = lane >> 4,
              ln = lane & 15;
    const int i0 = blockIdx.x * 64;
    const int row = tid >> 2, c = tid & 3;
    const int wofs = row * 32 + ((c + (row >> 1)) & 3) * 8;

    f32x4 acc[4];
#pragma unroll
    for (int ns = 0; ns < 4; ++ns) acc[ns] = (f32x4){0.f, 0.f, 0.f, 0.f};

    const int ar = wave * 16 + ln;
    const int aofs = ar * 32 + ((quad + (ar >> 1)) & 3) * 8;
    int bofs[4];
#pragma unroll
    for (int ns = 0; ns < 4; ++ns) {
        const int br = ns * 16 + ln;
        bofs[ns] = br * 32 + ((quad + (br >> 1)) & 3) * 8;
    }

    for (int kt = 0; kt < 16; ++kt) {
        __syncthreads();
        {
            const float* src = xs + (size_t)(i0 + row) * DIM + kt * 32 + c * 8;
            const float4 f0 = *(const float4*)src, f1 = *(const float4*)(src + 4);
            float v[8] = {f0.x, f0.y, f0.z, f0.w, f1.x, f1.y, f1.z, f1.w};
            u16x8 h8, m8, l8;
            split3(v, h8, m8, l8);
            *(u16x8*)(lAh + wofs) = h8;
            *(u16x8*)(lAm + wofs) = m8;
            *(u16x8*)(lAl + wofs) = l8;
        }
        {
            const float* src = W1 + (size_t)row * DIM + kt * 32 + c * 8;
            const float4 f0 = *(const float4*)src, f1 = *(const float4*)(src + 4);
            float v[8] = {f0.x, f0.y, f0.z, f0.w, f1.x, f1.y, f1.z, f1.w};
            u16x8 h8, m8, l8;
            split3(v, h8, m8, l8);
            *(u16x8*)(lWh + wofs) = h8;
            *(u16x8*)(lWm + wofs) = m8;
            *(u16x8*)(lWl + wofs) = l8;
        }
        __syncthreads();
        const bf16x8 ah = *(const bf16x8*)(lAh + aofs);
        const bf16x8 am = *(const bf16x8*)(lAm + aofs);
        const bf16x8 al = *(const bf16x8*)(lAl + aofs);
#pragma unroll
        for (int ns = 0; ns < 4; ++ns) {
            const bf16x8 bh = *(const bf16x8*)(lWh + bofs[ns]);
            const bf16x8 bm = *(const bf16x8*)(lWm + bofs[ns]);
            const bf16x8 bl = *(const bf16x8*)(lWl + bofs[ns]);
            acc[ns] = __builtin_amdgcn_mfma_f32_16x16x32_bf16(ah, bh, acc[ns], 0, 0, 0);
            acc[ns] = __builtin_amdgcn_mfma_f32_16x16x32_bf16(ah, bm, acc[ns], 0, 0, 0);
            acc[ns] = __builtin_amdgcn_mfma_f32_16x16x32_bf16(am, bh, acc[ns], 0, 0, 0);
            acc[ns] = __builtin_amdgcn_mfma_f32_16x16x32_bf16(am, bm, acc[ns], 0, 0, 0);
            acc[ns] = __builtin_amdgcn_mfma_f32_16x16x32_bf16(ah, bl, acc[ns], 0, 0, 0);
            acc[ns] = __builtin_amdgcn_mfma_f32_16x16x32_bf16(al, bh, acc[ns], 0, 0, 0);
        }
    }
#pragma unroll
    for (int ns = 0; ns < 4; ++ns)
#pragma unroll
        for (int v = 0; v < 4; ++v)
            P[(size_t)(i0 + wave * 16 + quad * 4 + v) * 64 + ns * 16 + ln] = acc[ns][v];
}

// ---------------------------------------------------------------- k_tail
// Row-per-lane exact fp32 chain P -> zs, G2. Weights via uniform scalar
// loads; inner k unrolled over register arrays; NO shfl. 128 blocks x 64.
__global__ __launch_bounds__(64) void k_tail(const float* __restrict__ P,
                                             const unsigned long long* __restrict__ nn,
                                             const float* __restrict__ b1,
                                             const float* __restrict__ W2,
                                             const float* __restrict__ b2,
                                             const float* __restrict__ W3,
                                             const float* __restrict__ b3,
                                             const float* __restrict__ D1,
                                             const float* __restrict__ d1,
                                             const float* __restrict__ D2,
                                             const float* __restrict__ d2,
                                             float* __restrict__ out_zs,
                                             float* __restrict__ G2) {
    __shared__ float ls[32 * 64];  // [o][lane], per-lane private column
    const int lane = threadIdx.x;
    const int row = blockIdx.x * 64 + lane;
    const unsigned int nnr = (unsigned int)(nn[row] & 0xFFFFFFFFull) & 8191u;
    const float* pr = P + (size_t)row * 64;
    const float* p0 = P + (size_t)nnr * 64;

    float h1[64], th1[64];
#pragma unroll
    for (int k = 0; k < 64; k += 4) {
        const float4 a = *(const float4*)(pr + k);
        const float4 b = *(const float4*)(p0 + k);
        const float pv[4] = {a.x, a.y, a.z, a.w}, qv[4] = {b.x, b.y, b.z, b.w};
#pragma unroll
        for (int j = 0; j < 4; ++j) {
            const float a1 = qv[j] + b1[k + j];
            h1[k + j] = fmaxf(a1, 0.f);
            th1[k + j] = (a1 > 0.f) ? (pv[j] - qv[j]) : 0.f;
        }
    }
    // layer 2 (JVP): s = relu(a2) + (a2>0)*u2
    for (int o = 0; o < 32; o += 2) {
        float a0 = b2[o], u0 = 0.f, a1v = b2[o + 1], u1v = 0.f;
        const float* w0 = W2 + o * 64;
        const float* w1 = W2 + (o + 1) * 64;
#pragma unroll
        for (int k = 0; k < 64; ++k) {
            a0 = fmaf(h1[k], w0[k], a0);
            u0 = fmaf(th1[k], w0[k], u0);
            a1v = fmaf(h1[k], w1[k], a1v);
            u1v = fmaf(th1[k], w1[k], u1v);
        }
        ls[o * 64 + lane] = fmaxf(a0, 0.f) + ((a0 > 0.f) ? u0 : 0.f);
        ls[(o + 1) * 64 + lane] = fmaxf(a1v, 0.f) + ((a1v > 0.f) ? u1v : 0.f);
    }
    float sv[32];
#pragma unroll
    for (int k = 0; k < 32; ++k) sv[k] = ls[k * 64 + lane];
    // z = s @ W3^T + b3  -> output zs
    for (int o = 0; o < 32; o += 2) {
        float z0 = b3[o], z1 = b3[o + 1];
        const float* w0 = W3 + o * 32;
        const float* w1 = W3 + (o + 1) * 32;
#pragma unroll
        for (int k = 0; k < 32; ++k) {
            z0 = fmaf(sv[k], w0[k], z0);
            z1 = fmaf(sv[k], w1[k], z1);
        }
        out_zs[(size_t)row * 32 + o] = z0;
        out_zs[(size_t)row * 32 + o + 1] = z1;
        ls[o * 64 + lane] = z0;
        ls[(o + 1) * 64 + lane] = z1;
    }
    float zv[32];
#pragma unroll
    for (int k = 0; k < 32; ++k) zv[k] = ls[k * 64 + lane];
    // decoder layer 1
    for (int o = 0; o < 32; o += 2) {
        float g0 = d1[o], g1v = d1[o + 1];
        const float* w0 = D1 + o * 32;
        const float* w1 = D1 + (o + 1) * 32;
#pragma unroll
        for (int k = 0; k < 32; ++k) {
            g0 = fmaf(zv[k], w0[k], g0);
            g1v = fmaf(zv[k], w1[k], g1v);
        }
        ls[o * 64 + lane] = fmaxf(g0, 0.f);
        ls[(o + 1) * 64 + lane] = fmaxf(g1v, 0.f);
    }
    float gv[32];
#pragma unroll
    for (int k = 0; k < 32; ++k) gv[k] = ls[k * 64 + lane];
    // decoder layer 2 -> G2
    for (int o = 0; o < 64; o += 2) {
        float g0 = d2[o], g1v = d2[o + 1];
        const float* w0 = D2 + o * 32;
        const float* w1 = D2 + (o + 1) * 32;
#pragma unroll
        for (int k = 0; k < 32; ++k) {
            g0 = fmaf(gv[k], w0[k], g0);
            g1v = fmaf(gv[k], w1[k], g1v);
        }
        G2[(size_t)row * 64 + o] = fmaxf(g0, 0.f);
        G2[(size_t)row * 64 + o + 1] = fmaxf(g1v, 0.f);
    }
}

// ---------------------------------------------------------------- k_dec
// x_hats = G2 @ D3^T + d3 via 2-way-split bf16 MFMA (3 products, err ~1e-6,
// no gates downstream). Block 128 rows x 128 cols, K=64. grid (64,4).
__global__ __launch_bounds__(256) void k_dec(const float* __restrict__ G2,
                                             const float* __restrict__ D3,
                                             const float* __restrict__ d3,
                                             float* __restrict__ xhat) {
    __shared__ __align__(16) unsigned short lGh[128 * 64], lGl[128 * 64];
    __shared__ __align__(16) unsigned short lDh[128 * 64], lDl[128 * 64];
    const int tid = threadIdx.x, wave = tid >> 6, lane = tid & 63, quad = lane >> 4,
              ln = lane & 15;
    const int i0 = blockIdx.x * 128, nbase = blockIdx.y * 128;
    const int m_off = (wave & 1) * 64, n_off = (wave >> 1) * 64;
#pragma unroll
    for (int r = 0; r < 4; ++r) {
        const int g = r * 256 + tid;
        const int row = g >> 3, cIdx = g & 7, half = cIdx >> 2, cc = cIdx & 3;
        const int wofs = row * 64 + half * 32 + ((cc + (row >> 1)) & 3) * 8;
        {
            const float* src = G2 + (size_t)(i0 + row) * 64 + cIdx * 8;
            const float4 f0 = *(const float4*)src, f1 = *(const float4*)(src + 4);
            float v[8] = {f0.x, f0.y, f0.z, f0.w, f1.x, f1.y, f1.z, f1.w};
            u16x8 h8, l8;
            split2(v, h8, l8);
            *(u16x8*)(lGh + wofs) = h8;
            *(u16x8*)(lGl + wofs) = l8;
        }
        {
            const float* src = D3 + (size_t)(nbase + row) * 64 + cIdx * 8;
            const float4 f0 = *(const float4*)src, f1 = *(const float4*)(src + 4);
            float v[8] = {f0.x, f0.y, f0.z, f0.w, f1.x, f1.y, f1.z, f1.w};
            u16x8 h8, l8;
            split2(v, h8, l8);
            *(u16x8*)(lDh + wofs) = h8;
            *(u16x8*)(lDl + wofs) = l8;
        }
    }
    __syncthreads();
    f32x4 acc[4][4];
#pragma unroll
    for (int a = 0; a < 4; ++a)
#pragma unroll
        for (int c = 0; c < 4; ++c) acc[a][c] = (f32x4){0.f, 0.f, 0.f, 0.f};
#pragma unroll
    for (int kk = 0; kk < 2; ++kk) {
        bf16x8 ah[4], al[4], bh[4], bl[4];
#pragma unroll
        for (int ms = 0; ms < 4; ++ms) {
            const int ar = m_off + ms * 16 + ln;
            const int aofs = ar * 64 + kk * 32 + ((quad + (ar >> 1)) & 3) * 8;
            ah[ms] = *(const bf16x8*)(lGh + aofs);
            al[ms] = *(const bf16x8*)(lGl + aofs);
        }
#pragma unroll
        for (int ns = 0; ns < 4; ++ns) {
            const int br = n_off + ns * 16 + ln;
            const int bofs = br * 64 + kk * 32 + ((quad + (br >> 1)) & 3) * 8;
            bh[ns] = *(const bf16x8*)(lDh + bofs);
            bl[ns] = *(const bf16x8*)(lDl + bofs);
        }
#pragma unroll
        for (int ms = 0; ms < 4; ++ms)
#pragma unroll
            for (int ns = 0; ns < 4; ++ns) {
                acc[ms][ns] = __builtin_amdgcn_mfma_f32_16x16x32_bf16(
                    ah[ms], bh[ns], acc[ms][ns], 0, 0, 0);
                acc[ms][ns] = __builtin_amdgcn_mfma_f32_16x16x32_bf16(
                    ah[ms], bl[ns], acc[ms][ns], 0, 0, 0);
                acc[ms][ns] = __builtin_amdgcn_mfma_f32_16x16x32_bf16(
                    al[ms], bh[ns], acc[ms][ns], 0, 0, 0);
            }
    }
    float d3f[4];
#pragma unroll
    for (int ns = 0; ns < 4; ++ns) d3f[ns] = d3[nbase + n_off + ns * 16 + ln];
#pragma unroll
    for (int ms = 0; ms < 4; ++ms)
#pragma unroll
        for (int ns = 0; ns < 4; ++ns)
#pragma unroll
            for (int v = 0; v < 4; ++v) {
                const int m = m_off + ms * 16 + quad * 4 + v;
                const int n = n_off + ns * 16 + ln;
                xhat[(size_t)(i0 + m) * DIM + nbase + n] = acc[ms][ns][v] + d3f[ns];
            }
}

extern "C" void kernel_launch(void* const* d_in, const int* in_sizes, int n_in,
                              void* d_out, int out_size, void* d_ws, size_t ws_size,
                              hipStream_t stream) {
    const float* xs = (const float*)d_in[0];
    const float* W1 = (const float*)d_in[1];
    const float* b1 = (const float*)d_in[2];
    const float* W2 = (const float*)d_in[3];
    const float* b2 = (const float*)d_in[4];
    const float* W3 = (const float*)d_in[5];
    const float* b3 = (const float*)d_in[6];
    const float* D1 = (const float*)d_in[7];
    const float* d1 = (const float*)d_in[8];
    const float* D2 = (const float*)d_in[9];
    const float* d2 = (const float*)d_in[10];
    const float* D3 = (const float*)d_in[11];
    const float* d3 = (const float*)d_in[12];

    // workspace (12.7 MB, same as R7): sq | nn | xs_hi | xs_mo (dead after
    // k_nn; P and G2 overlay it — k_p reads fp32 xs directly)
    char* ws = (char*)d_ws;
    float* sq = (float*)(ws);                                     // @0        32 KB
    unsigned long long* nn = (unsigned long long*)(ws + 32768);   // @32768    64 KB
    unsigned short* xs_hi = (unsigned short*)(ws + 131072);       // @131072    8 MB
    unsigned short* xs_mo = (unsigned short*)(ws + 8519680);      // @8519680   8 MB
    float* P = (float*)(ws + 8519680);                            // overlays xs_mo
    float* G2 = (float*)(ws + 10616832);                          // +2 MB

    float* xhat = (float*)d_out;
    float* zs = (float*)d_out + (size_t)NROWS * DIM;

    hipLaunchKernelGGL(k_prep, dim3(2048), dim3(256), 0, stream, xs, xs_hi, xs_mo, sq, nn);
    hipLaunchKernelGGL(k_nn, dim3(2112), dim3(256), 0, stream, xs_hi, xs_mo, sq, nn);
    hipLaunchKernelGGL(k_p, dim3(128), dim3(256), 0, stream, xs, W1, P);
    hipLaunchKernelGGL(k_tail, dim3(128), dim3(64), 0, stream, P, nn, b1, W2, b2, W3,
                       b3, D1, d1, D2, d2, zs, G2);
    hipLaunchKernelGGL(k_dec, dim3(64, 4), dim3(256), 0, stream, G2, D3, d3, xhat);
}